// Round 1
// baseline (34462.961 us; speedup 1.0000x reference)
//
#include <hip/hip_runtime.h>
#include <hip/hip_bf16.h>
#include <stdint.h>

#define T_STEPS 8192
#define HID     1024
#define IN_F    2048
#define N3H     3072   // 3*HID

// ---------------------------------------------------------------------------
// Init: zero the (tag,value) pair buffers. tag=0, value=0.0f == "h_0 ready".
// ---------------------------------------------------------------------------
__global__ void init_pairs(unsigned long long* pairs) {
    int i = blockIdx.x * blockDim.x + threadIdx.x;
    if (i < 2 * HID) pairs[i] = 0ull;
}

// ---------------------------------------------------------------------------
// Phase 1: gi[t, j'] = x[t] . w_ih[j'] + b_ih[j']   (x = [features | reward])
// fp32 tiled GEMM, 64x64 tile, BK=32, 4x4 per thread, 256 threads.
// K split: k<2048 from features, k==2048 handled in epilogue via rewards.
// ---------------------------------------------------------------------------
#define GBM 64
#define GBN 64
#define GBK 32

__global__ __launch_bounds__(256) void gi_gemm(
    const float* __restrict__ feat,   // [8192][2048]
    const float* __restrict__ rew,    // [8192]
    const float* __restrict__ w_ih,   // [3072][2049]  (row len 2049: NOT 16B aligned per row)
    const float* __restrict__ b_ih,   // [3072]
    float* __restrict__ gi)           // [8192][3072]
{
    __shared__ float As[GBK][GBM + 4];
    __shared__ float Bs[GBK][GBN + 4];

    const int tid = threadIdx.x;
    const int n0 = blockIdx.x * GBN;   // N dim (3072/64 = 48)
    const int t0 = blockIdx.y * GBM;   // M dim (8192/64 = 128)
    const int tx = tid & 15, ty = tid >> 4;
    const int lr = tid >> 3;           // 0..31
    const int lc = (tid & 7) * 4;      // 0,4,...,28

    float acc[4][4] = {{0.f}};

    for (int k0 = 0; k0 < IN_F; k0 += GBK) {
#pragma unroll
        for (int hh = 0; hh < 2; hh++) {
            const int r = lr + 32 * hh;
            // A: features rows t0+r, 16B-aligned (row length 2048)
            const float4 a = *(const float4*)(feat + (size_t)(t0 + r) * IN_F + k0 + lc);
            As[lc + 0][r] = a.x; As[lc + 1][r] = a.y;
            As[lc + 2][r] = a.z; As[lc + 3][r] = a.w;
            // B: w_ih rows n0+r — row length 2049 (odd) so scalar loads (alignment)
            const float* brow = w_ih + (size_t)(n0 + r) * (IN_F + 1) + k0 + lc;
            Bs[lc + 0][r] = brow[0]; Bs[lc + 1][r] = brow[1];
            Bs[lc + 2][r] = brow[2]; Bs[lc + 3][r] = brow[3];
        }
        __syncthreads();
#pragma unroll
        for (int kk = 0; kk < GBK; kk++) {
            const float4 a = *(const float4*)&As[kk][ty * 4];
            const float4 b = *(const float4*)&Bs[kk][tx * 4];
            acc[0][0] += a.x * b.x; acc[0][1] += a.x * b.y; acc[0][2] += a.x * b.z; acc[0][3] += a.x * b.w;
            acc[1][0] += a.y * b.x; acc[1][1] += a.y * b.y; acc[1][2] += a.y * b.z; acc[1][3] += a.y * b.w;
            acc[2][0] += a.z * b.x; acc[2][1] += a.z * b.y; acc[2][2] += a.z * b.z; acc[2][3] += a.z * b.w;
            acc[3][0] += a.w * b.x; acc[3][1] += a.w * b.y; acc[3][2] += a.w * b.z; acc[3][3] += a.w * b.w;
        }
        __syncthreads();
    }

    // epilogue: + rewards[t]*w_ih[j'][2048] + b_ih[j'], then store
    const int m = t0 + ty * 4;
    const int n = n0 + tx * 4;
    float wlast[4], bi[4];
#pragma unroll
    for (int c = 0; c < 4; c++) {
        wlast[c] = w_ih[(size_t)(n + c) * (IN_F + 1) + IN_F];
        bi[c]    = b_ih[n + c];
    }
#pragma unroll
    for (int r = 0; r < 4; r++) {
        const float rwv = rew[m + r];
        float4 v;
        v.x = acc[r][0] + rwv * wlast[0] + bi[0];
        v.y = acc[r][1] + rwv * wlast[1] + bi[1];
        v.z = acc[r][2] + rwv * wlast[2] + bi[2];
        v.w = acc[r][3] + rwv * wlast[3] + bi[3];
        *(float4*)(gi + (size_t)(m + r) * N3H + n) = v;
    }
}

// ---------------------------------------------------------------------------
// Phase 2: persistent GRU scan. 256 wgs x 256 threads; wg g owns j in [4g,4g+4).
// Recurrent weight rows live in LDS (48 KB/wg, 12 MB chip-wide).
// Cross-wg h exchange: per-j 8-byte (tag,value) words, double-buffered,
// relaxed agent-scope atomics. tag==i means "h value for iteration i".
// ---------------------------------------------------------------------------
__global__ __launch_bounds__(256, 2) void gru_scan(
    const float* __restrict__ gi,     // [8192][3072]
    const float* __restrict__ w_hh,   // [3072][1024]
    const float* __restrict__ b_hh,   // [3072]
    unsigned long long* pairs,        // [2][1024]
    float* __restrict__ out)          // [1024]
{
    __shared__ float4 w_lds[3][4][HID / 4];  // [gate][j_local][k/4]  48 KB
    __shared__ float4 h_lds[HID / 4];        // 4 KB

    const int tid  = threadIdx.x;
    const int g    = blockIdx.x;      // 0..255
    const int j0   = g * 4;
    const int wave = tid >> 6;
    const int lane = tid & 63;
    const int myj  = j0 + wave;       // wave w owns output element j0+w

    // stage this wg's 12 weight rows (gate in {r,z,n} x 4 local j) into LDS
#pragma unroll
    for (int r = 0; r < 12; r++) {
        const int gate = r >> 2, jl = r & 3;
        const float4* src = (const float4*)(w_hh + (size_t)(gate * HID + j0 + jl) * HID);
        w_lds[gate][jl][tid] = src[tid];
    }
    float b_r = 0.f, b_z = 0.f, b_n = 0.f;
    if (lane == 0) {
        b_r = b_hh[myj];
        b_z = b_hh[HID + myj];
        b_n = b_hh[2 * HID + myj];
    }
    __syncthreads();

    for (int i = 0; i < T_STEPS; i++) {
        const int t = T_STEPS - 1 - i;           // reverse scan
        unsigned long long* buf  = pairs + (size_t)(i & 1) * HID;
        unsigned long long* nbuf = pairs + (size_t)((i + 1) & 1) * HID;

        // prefetch gi row for this wave's j (registers survive the spin)
        float gi_r = 0.f, gi_z = 0.f, gi_n = 0.f;
        if (lane == 0) {
            const float* girow = gi + (size_t)t * N3H;
            gi_r = girow[myj];
            gi_z = girow[HID + myj];
            gi_n = girow[2 * HID + myj];
        }

        // poll my 4 (tag,value) words until tag == i; fused flag+data, no fences
        {
            unsigned long long* p = buf + tid * 4;
            const unsigned int want = (unsigned int)i;
            unsigned long long v0, v1, v2, v3;
            for (;;) {
                v0 = __hip_atomic_load(p + 0, __ATOMIC_RELAXED, __HIP_MEMORY_SCOPE_AGENT);
                v1 = __hip_atomic_load(p + 1, __ATOMIC_RELAXED, __HIP_MEMORY_SCOPE_AGENT);
                v2 = __hip_atomic_load(p + 2, __ATOMIC_RELAXED, __HIP_MEMORY_SCOPE_AGENT);
                v3 = __hip_atomic_load(p + 3, __ATOMIC_RELAXED, __HIP_MEMORY_SCOPE_AGENT);
                if ((unsigned int)(v0 >> 32) == want && (unsigned int)(v1 >> 32) == want &&
                    (unsigned int)(v2 >> 32) == want && (unsigned int)(v3 >> 32) == want)
                    break;
            }
            float4 hv;
            hv.x = __uint_as_float((unsigned int)v0);
            hv.y = __uint_as_float((unsigned int)v1);
            hv.z = __uint_as_float((unsigned int)v2);
            hv.w = __uint_as_float((unsigned int)v3);
            h_lds[tid] = hv;
        }
        __syncthreads();

        // wave `wave` computes the 3 recurrent dots for j = myj
        float ar = 0.f, az = 0.f, an = 0.f;
        const float4* wr = w_lds[0][wave];
        const float4* wz = w_lds[1][wave];
        const float4* wn = w_lds[2][wave];
#pragma unroll
        for (int m4 = 0; m4 < 4; m4++) {
            const int idx = lane + 64 * m4;
            const float4 h4 = h_lds[idx];
            const float4 r4 = wr[idx];
            const float4 z4 = wz[idx];
            const float4 n4 = wn[idx];
            ar += h4.x * r4.x + h4.y * r4.y + h4.z * r4.z + h4.w * r4.w;
            az += h4.x * z4.x + h4.y * z4.y + h4.z * z4.z + h4.w * z4.w;
            an += h4.x * n4.x + h4.y * n4.y + h4.z * n4.z + h4.w * n4.w;
        }
#pragma unroll
        for (int off = 32; off > 0; off >>= 1) {
            ar += __shfl_down(ar, off);
            az += __shfl_down(az, off);
            an += __shfl_down(an, off);
        }

        if (lane == 0) {
            const float hjold = ((const float*)h_lds)[myj];
            const float r = 1.f / (1.f + __expf(-(gi_r + ar + b_r)));
            const float z = 1.f / (1.f + __expf(-(gi_z + az + b_z)));
            const float n = tanhf(gi_n + r * (an + b_n));
            const float hnew = (1.f - z) * n + z * hjold;
            if (i == T_STEPS - 1) {
                out[myj] = hnew;
            } else {
                const unsigned long long pk =
                    ((unsigned long long)(unsigned int)(i + 1) << 32) |
                    (unsigned long long)__float_as_uint(hnew);
                __hip_atomic_store(nbuf + myj, pk, __ATOMIC_RELAXED, __HIP_MEMORY_SCOPE_AGENT);
            }
        }
        __syncthreads();   // protect h_lds before next iteration's writes
    }
}

// ---------------------------------------------------------------------------
extern "C" void kernel_launch(void* const* d_in, const int* in_sizes, int n_in,
                              void* d_out, int out_size, void* d_ws, size_t ws_size,
                              hipStream_t stream) {
    const float* feat = (const float*)d_in[0];  // [8192,2048]
    const float* rew  = (const float*)d_in[1];  // [8192]
    const float* w_ih = (const float*)d_in[2];  // [3072,2049]
    const float* w_hh = (const float*)d_in[3];  // [3072,1024]
    const float* b_ih = (const float*)d_in[4];  // [3072]
    const float* b_hh = (const float*)d_in[5];  // [3072]
    float* out = (float*)d_out;                 // [1024]

    float* gi = (float*)d_ws;                                   // 96 MB
    unsigned long long* pairs =
        (unsigned long long*)((char*)d_ws + (size_t)T_STEPS * N3H * sizeof(float));

    hipLaunchKernelGGL(init_pairs, dim3(8), dim3(256), 0, stream, pairs);
    hipLaunchKernelGGL(gi_gemm, dim3(N3H / GBN, T_STEPS / GBM), dim3(256), 0, stream,
                       feat, rew, w_ih, b_ih, gi);
    hipLaunchKernelGGL(gru_scan, dim3(256), dim3(256), 0, stream,
                       gi, w_hh, b_hh, pairs, out);
}

// Round 2
// 34128.552 us; speedup vs baseline: 1.0098x; 1.0098x over previous
//
#include <hip/hip_runtime.h>
#include <hip/hip_bf16.h>
#include <stdint.h>

#define T_STEPS 8192
#define HID     1024
#define IN_F    2048
#define N3H     3072   // 3*HID

// ---------------------------------------------------------------------------
// Exchange format: one 32-bit word per h element. Low 2 mantissa bits carry
// the step tag (step & 3). Double-buffered; buffer (s&1) holds h for step s.
// Stale slot content in buffer (s&1) is from step s-2: (s-2)&3 != s&3, so a
// 2-bit tag disambiguates. Injected value error <= 3 ulp (~3.6e-7 rel).
// h_0 = 0.0f with tag 0 == bit pattern 0x00000000 -> init buffers to zero.
// ---------------------------------------------------------------------------
__global__ void init_pairs(unsigned int* pairs) {
    int i = blockIdx.x * blockDim.x + threadIdx.x;
    if (i < 2 * HID) pairs[i] = 0u;
}

// ---------------------------------------------------------------------------
// Phase 1: gi[t, j'] = x[t] . w_ih[j'] + b_ih[j']   (x = [features | reward])
// fp32 tiled GEMM, 64x64 tile, BK=32, 4x4 per thread, 256 threads.
// ---------------------------------------------------------------------------
#define GBM 64
#define GBN 64
#define GBK 32

__global__ __launch_bounds__(256) void gi_gemm(
    const float* __restrict__ feat,   // [8192][2048]
    const float* __restrict__ rew,    // [8192]
    const float* __restrict__ w_ih,   // [3072][2049]
    const float* __restrict__ b_ih,   // [3072]
    float* __restrict__ gi)           // [8192][3072]
{
    __shared__ float As[GBK][GBM + 4];
    __shared__ float Bs[GBK][GBN + 4];

    const int tid = threadIdx.x;
    const int n0 = blockIdx.x * GBN;
    const int t0 = blockIdx.y * GBM;
    const int tx = tid & 15, ty = tid >> 4;
    const int lr = tid >> 3;           // 0..31
    const int lc = (tid & 7) * 4;      // 0,4,...,28

    float acc[4][4] = {{0.f}};

    for (int k0 = 0; k0 < IN_F; k0 += GBK) {
#pragma unroll
        for (int hh = 0; hh < 2; hh++) {
            const int r = lr + 32 * hh;
            const float4 a = *(const float4*)(feat + (size_t)(t0 + r) * IN_F + k0 + lc);
            As[lc + 0][r] = a.x; As[lc + 1][r] = a.y;
            As[lc + 2][r] = a.z; As[lc + 3][r] = a.w;
            const float* brow = w_ih + (size_t)(n0 + r) * (IN_F + 1) + k0 + lc;
            Bs[lc + 0][r] = brow[0]; Bs[lc + 1][r] = brow[1];
            Bs[lc + 2][r] = brow[2]; Bs[lc + 3][r] = brow[3];
        }
        __syncthreads();
#pragma unroll
        for (int kk = 0; kk < GBK; kk++) {
            const float4 a = *(const float4*)&As[kk][ty * 4];
            const float4 b = *(const float4*)&Bs[kk][tx * 4];
            acc[0][0] += a.x * b.x; acc[0][1] += a.x * b.y; acc[0][2] += a.x * b.z; acc[0][3] += a.x * b.w;
            acc[1][0] += a.y * b.x; acc[1][1] += a.y * b.y; acc[1][2] += a.y * b.z; acc[1][3] += a.y * b.w;
            acc[2][0] += a.z * b.x; acc[2][1] += a.z * b.y; acc[2][2] += a.z * b.z; acc[2][3] += a.z * b.w;
            acc[3][0] += a.w * b.x; acc[3][1] += a.w * b.y; acc[3][2] += a.w * b.z; acc[3][3] += a.w * b.w;
        }
        __syncthreads();
    }

    const int m = t0 + ty * 4;
    const int n = n0 + tx * 4;
    float wlast[4], bi[4];
#pragma unroll
    for (int c = 0; c < 4; c++) {
        wlast[c] = w_ih[(size_t)(n + c) * (IN_F + 1) + IN_F];
        bi[c]    = b_ih[n + c];
    }
#pragma unroll
    for (int r = 0; r < 4; r++) {
        const float rwv = rew[m + r];
        float4 v;
        v.x = acc[r][0] + rwv * wlast[0] + bi[0];
        v.y = acc[r][1] + rwv * wlast[1] + bi[1];
        v.z = acc[r][2] + rwv * wlast[2] + bi[2];
        v.w = acc[r][3] + rwv * wlast[3] + bi[3];
        *(float4*)(gi + (size_t)(m + r) * N3H + n) = v;
    }
}

// ---------------------------------------------------------------------------
// Phase 2: persistent GRU scan. 256 wgs x 256 threads; wg g owns j in [4g,4g+4).
// Recurrent weight rows in LDS (48 KB/wg). h exchange: tagged fp32 words,
// double-buffered, relaxed agent-scope atomics. Coalesced poll: thread t
// polls words {t, t+256, t+512, t+768} (each wave load = 256 B contiguous).
// ---------------------------------------------------------------------------
__global__ __launch_bounds__(256, 2) void gru_scan(
    const float* __restrict__ gi,     // [8192][3072]
    const float* __restrict__ w_hh,   // [3072][1024]
    const float* __restrict__ b_hh,   // [3072]
    unsigned int* pairs,              // [2][1024] tagged fp32
    float* __restrict__ out)          // [1024]
{
    __shared__ float4 w_lds[3][4][HID / 4];  // [gate][j_local][k/4]  48 KB
    __shared__ float4 h_lds[HID / 4];        // 4 KB

    const int tid  = threadIdx.x;
    const int g    = blockIdx.x;      // 0..255
    const int j0   = g * 4;
    const int wave = tid >> 6;
    const int lane = tid & 63;
    const int myj  = j0 + wave;       // wave w owns output element j0+w

    // stage this wg's 12 weight rows into LDS
#pragma unroll
    for (int r = 0; r < 12; r++) {
        const int gate = r >> 2, jl = r & 3;
        const float4* src = (const float4*)(w_hh + (size_t)(gate * HID + j0 + jl) * HID);
        w_lds[gate][jl][tid] = src[tid];
    }
    float b_r = 0.f, b_z = 0.f, b_n = 0.f;
    if (lane == 0) {
        b_r = b_hh[myj];
        b_z = b_hh[HID + myj];
        b_n = b_hh[2 * HID + myj];
    }
    __syncthreads();

    float* h_f = (float*)h_lds;

    for (int i = 0; i < T_STEPS; i++) {
        const int t = T_STEPS - 1 - i;           // reverse scan
        unsigned int* buf  = pairs + (size_t)(i & 1) * HID;
        unsigned int* nbuf = pairs + (size_t)((i + 1) & 1) * HID;

        // prefetch gi row entries for this wave's j (issued before the spin)
        float gi_r = 0.f, gi_z = 0.f, gi_n = 0.f;
        if (lane == 0) {
            const float* girow = gi + (size_t)t * N3H;
            gi_r = girow[myj];
            gi_z = girow[HID + myj];
            gi_n = girow[2 * HID + myj];
        }

        // coalesced poll of 4 words/thread until all carry tag (i&3)
        {
            const unsigned int want = (unsigned int)(i & 3);
            unsigned int v0, v1, v2, v3;
            for (;;) {
                v0 = __hip_atomic_load(buf + tid,       __ATOMIC_RELAXED, __HIP_MEMORY_SCOPE_AGENT);
                v1 = __hip_atomic_load(buf + tid + 256, __ATOMIC_RELAXED, __HIP_MEMORY_SCOPE_AGENT);
                v2 = __hip_atomic_load(buf + tid + 512, __ATOMIC_RELAXED, __HIP_MEMORY_SCOPE_AGENT);
                v3 = __hip_atomic_load(buf + tid + 768, __ATOMIC_RELAXED, __HIP_MEMORY_SCOPE_AGENT);
                if (((v0 & 3u) == want) && ((v1 & 3u) == want) &&
                    ((v2 & 3u) == want) && ((v3 & 3u) == want))
                    break;
                __builtin_amdgcn_s_sleep(1);   // backoff: cut spin pressure on L3
            }
            h_f[tid      ] = __uint_as_float(v0);
            h_f[tid + 256] = __uint_as_float(v1);
            h_f[tid + 512] = __uint_as_float(v2);
            h_f[tid + 768] = __uint_as_float(v3);
        }
        __syncthreads();

        // wave `wave` computes the 3 recurrent dots for j = myj
        float ar = 0.f, az = 0.f, an = 0.f;
        const float4* wr = w_lds[0][wave];
        const float4* wz = w_lds[1][wave];
        const float4* wn = w_lds[2][wave];
#pragma unroll
        for (int m4 = 0; m4 < 4; m4++) {
            const int idx = lane + 64 * m4;
            const float4 h4 = h_lds[idx];
            const float4 r4 = wr[idx];
            const float4 z4 = wz[idx];
            const float4 n4 = wn[idx];
            ar += h4.x * r4.x + h4.y * r4.y + h4.z * r4.z + h4.w * r4.w;
            az += h4.x * z4.x + h4.y * z4.y + h4.z * z4.z + h4.w * z4.w;
            an += h4.x * n4.x + h4.y * n4.y + h4.z * n4.z + h4.w * n4.w;
        }
#pragma unroll
        for (int off = 32; off > 0; off >>= 1) {
            ar += __shfl_down(ar, off);
            az += __shfl_down(az, off);
            an += __shfl_down(an, off);
        }

        if (lane == 0) {
            const float hjold = h_f[myj];
            const float r = 1.f / (1.f + __expf(-(gi_r + ar + b_r)));
            const float z = 1.f / (1.f + __expf(-(gi_z + az + b_z)));
            const float n = tanhf(gi_n + r * (an + b_n));
            const float hnew = (1.f - z) * n + z * hjold;
            if (i == T_STEPS - 1) {
                out[myj] = hnew;
            } else {
                // pack: clear low 2 mantissa bits, insert tag (i+1)&3
                const unsigned int pk =
                    (__float_as_uint(hnew) & ~3u) | (unsigned int)((i + 1) & 3);
                __hip_atomic_store(nbuf + myj, pk, __ATOMIC_RELAXED, __HIP_MEMORY_SCOPE_AGENT);
            }
        }
        __syncthreads();   // protect h_lds before next iteration's poll writes
    }
}

// ---------------------------------------------------------------------------
extern "C" void kernel_launch(void* const* d_in, const int* in_sizes, int n_in,
                              void* d_out, int out_size, void* d_ws, size_t ws_size,
                              hipStream_t stream) {
    const float* feat = (const float*)d_in[0];  // [8192,2048]
    const float* rew  = (const float*)d_in[1];  // [8192]
    const float* w_ih = (const float*)d_in[2];  // [3072,2049]
    const float* w_hh = (const float*)d_in[3];  // [3072,1024]
    const float* b_ih = (const float*)d_in[4];  // [3072]
    const float* b_hh = (const float*)d_in[5];  // [3072]
    float* out = (float*)d_out;                 // [1024]

    float* gi = (float*)d_ws;                                   // 96 MB
    unsigned int* pairs =
        (unsigned int*)((char*)d_ws + (size_t)T_STEPS * N3H * sizeof(float));

    hipLaunchKernelGGL(init_pairs, dim3(8), dim3(256), 0, stream, pairs);
    hipLaunchKernelGGL(gi_gemm, dim3(N3H / GBN, T_STEPS / GBM), dim3(256), 0, stream,
                       feat, rew, w_ih, b_ih, gi);
    hipLaunchKernelGGL(gru_scan, dim3(256), dim3(256), 0, stream,
                       gi, w_hh, b_hh, pairs, out);
}